// Round 4
// baseline (107.210 us; speedup 1.0000x reference)
//
#include <hip/hip_runtime.h>

// SDT forward. Phase 1: logits = x@W via bf16 split (xh@wh + xh@wl + xl@wh),
// barrier-free K-loop, A-frags converted in registers, B-frags from L2.
// Phase 2: sigmoid+reg, tree path-products (grouped), out = P@value via bf16 MFMA.
// MFMA 16x16x32_bf16 layouts (HW-verified, rounds 2-3 passed):
//   A/B^T: lane&15 -> row, (lane>>4)*8 -> k ;  C/D: col=lane&15, row=(lane>>4)*4+reg

typedef __attribute__((ext_vector_type(8))) short short8;
typedef __attribute__((ext_vector_type(4))) float floatx4;

constexpr int O = 64;
constexpr int PSTR = 280;   // P_bf row stride (shorts): 560 B, 16B-aligned, 2-way banks
constexpr int LSTR = 260;   // L_s row stride (floats)

__device__ __forceinline__ short f2bf(float f) {
  unsigned u = __builtin_bit_cast(unsigned, f);
  u += 0x7fffu + ((u >> 16) & 1u);          // RNE
  return (short)(u >> 16);
}
__device__ __forceinline__ float bf2f(short h) {
  unsigned u = ((unsigned)(unsigned short)h) << 16;
  return __builtin_bit_cast(float, u);
}
__device__ __forceinline__ void cvt8(float4 a, float4 b, short8& h, short8& l) {
  float f[8] = {a.x, a.y, a.z, a.w, b.x, b.y, b.z, b.w};
#pragma unroll
  for (int i = 0; i < 8; ++i) {
    short hh = f2bf(f[i]);
    h[i] = hh;
    l[i] = f2bf(f[i] - bf2f(hh));
  }
}

// ---- pre: W^T hi/lo bf16, value^T bf16, zero reg ----
__global__ void sdt_pre(const float* __restrict__ Ws, const float* __restrict__ value,
                        short* __restrict__ wth, short* __restrict__ wtl,
                        short* __restrict__ vt, float* __restrict__ reg_slot) {
  int n = blockIdx.x;      // 0..255
  int k = threadIdx.x;     // 0..511
  float f = (n < 255) ? Ws[k * 255 + n] : 0.f;
  short h = f2bf(f);
  wth[n * 512 + k] = h;
  wtl[n * 512 + k] = f2bf(f - bf2f(h));
  if (n < 64 && k < 256) vt[n * 256 + k] = f2bf(value[k * O + n]);
  if (n == 0 && k == 0) *reg_slot = 0.f;
}

__global__ __launch_bounds__(512, 2) void sdt_main(
    const float* __restrict__ x, const short* __restrict__ wth,
    const short* __restrict__ wtl, const short* __restrict__ vt,
    const float* __restrict__ bs, float* __restrict__ out,
    float* __restrict__ reg_out)
{
  __shared__ float L_s[32 * LSTR];    // 33280 f = 133 KB... (32*260*4 = 33,280*4? no: bytes = 33280*4/… ) // 32*260 floats
  __shared__ short P_bf[32 * PSTR];   // bf16 path-products, A-frag layout
  __shared__ float red_s[8];

  const int t = threadIdx.x, lane = t & 63, w = t >> 6;   // 8 waves
  const int q = lane >> 4, r16 = lane & 15;
  const int R0 = blockIdx.x * 32;

  // ---------------- Phase 1: barrier-free GEMM ----------------
  const short* pwh0 = wth + (size_t)(w * 32 + r16) * 512 + q * 8;
  const short* pwl0 = wtl + (size_t)(w * 32 + r16) * 512 + q * 8;
  const short* pwh1 = pwh0 + 16 * 512;
  const short* pwl1 = pwl0 + 16 * 512;
  const float* px0 = x + (size_t)(R0 + r16) * 512 + q * 8;
  const float* px1 = px0 + 16 * 512;

  floatx4 acc00 = {0,0,0,0}, acc01 = {0,0,0,0}, acc10 = {0,0,0,0}, acc11 = {0,0,0,0};

  short8 Bh0 = *(const short8*)(pwh0), Bl0 = *(const short8*)(pwl0);
  short8 Bh1 = *(const short8*)(pwh1), Bl1 = *(const short8*)(pwl1);
  float4 Xa0 = *(const float4*)(px0),  Xb0 = *(const float4*)(px0 + 4);
  float4 Xa1 = *(const float4*)(px1),  Xb1 = *(const float4*)(px1 + 4);

#pragma unroll
  for (int c = 0; c < 16; ++c) {
    short8 nh0, nl0, nh1, nl1;
    float4 na0, nb0, na1, nb1;
    if (c < 15) {
      const int o = (c + 1) * 32;
      nh0 = *(const short8*)(pwh0 + o); nl0 = *(const short8*)(pwl0 + o);
      nh1 = *(const short8*)(pwh1 + o); nl1 = *(const short8*)(pwl1 + o);
      na0 = *(const float4*)(px0 + o);  nb0 = *(const float4*)(px0 + o + 4);
      na1 = *(const float4*)(px1 + o);  nb1 = *(const float4*)(px1 + o + 4);
    }
    short8 ah0, al0, ah1, al1;
    cvt8(Xa0, Xb0, ah0, al0);
    cvt8(Xa1, Xb1, ah1, al1);

    acc00 = __builtin_amdgcn_mfma_f32_16x16x32_bf16(ah0, Bh0, acc00, 0, 0, 0);
    acc01 = __builtin_amdgcn_mfma_f32_16x16x32_bf16(ah0, Bh1, acc01, 0, 0, 0);
    acc10 = __builtin_amdgcn_mfma_f32_16x16x32_bf16(ah1, Bh0, acc10, 0, 0, 0);
    acc11 = __builtin_amdgcn_mfma_f32_16x16x32_bf16(ah1, Bh1, acc11, 0, 0, 0);
    acc00 = __builtin_amdgcn_mfma_f32_16x16x32_bf16(ah0, Bl0, acc00, 0, 0, 0);
    acc01 = __builtin_amdgcn_mfma_f32_16x16x32_bf16(ah0, Bl1, acc01, 0, 0, 0);
    acc10 = __builtin_amdgcn_mfma_f32_16x16x32_bf16(ah1, Bl0, acc10, 0, 0, 0);
    acc11 = __builtin_amdgcn_mfma_f32_16x16x32_bf16(ah1, Bl1, acc11, 0, 0, 0);
    acc00 = __builtin_amdgcn_mfma_f32_16x16x32_bf16(al0, Bh0, acc00, 0, 0, 0);
    acc01 = __builtin_amdgcn_mfma_f32_16x16x32_bf16(al0, Bh1, acc01, 0, 0, 0);
    acc10 = __builtin_amdgcn_mfma_f32_16x16x32_bf16(al1, Bh0, acc10, 0, 0, 0);
    acc11 = __builtin_amdgcn_mfma_f32_16x16x32_bf16(al1, Bh1, acc11, 0, 0, 0);

    if (c < 15) {
      Bh0 = nh0; Bl0 = nl0; Bh1 = nh1; Bl1 = nl1;
      Xa0 = na0; Xb0 = nb0; Xa1 = na1; Xb1 = nb1;
    }
  }

  // epilogue: C frags -> L_s (cols w*32+r16, w*32+16+r16)
  {
    const int c0 = w * 32 + r16, c1 = c0 + 16;
#pragma unroll
    for (int r = 0; r < 4; ++r) {
      int row0 = q * 4 + r, row1 = row0 + 16;
      L_s[row0 * LSTR + c0] = acc00[r];
      L_s[row0 * LSTR + c1] = acc01[r];
      L_s[row1 * LSTR + c0] = acc10[r];
      L_s[row1 * LSTR + c1] = acc11[r];
    }
  }
  __syncthreads();

  // ---------------- Phase 2a: sigmoid (+bias), reg ----------------
  {
    const int col = t & 255, half = t >> 8;
    float rsum = 0.f;
    if (col < 255) {
      float b = bs[col];
      for (int r = half * 16; r < half * 16 + 16; ++r) {
        float z = L_s[r * LSTR + col] + b;
        float p = 1.f / (1.f + __expf(-z));
        L_s[r * LSTR + col] = p;                  // exclusive (col, half) owner
        rsum += __logf(fmaxf(p * (1.f - p), 1e-5f));
      }
      int dd = 31 - __clz(col + 1);
      rsum *= -0.5f / (8192.0f * (float)(1 << dd));
    }
#pragma unroll
    for (int off = 32; off; off >>= 1) rsum += __shfl_down(rsum, off, 64);
    if (lane == 0) red_s[w] = rsum;
  }
  __syncthreads();
  if (t == 0) {
    float s = 0.f;
#pragma unroll
    for (int i = 0; i < 8; ++i) s += red_s[i];
    atomicAdd(reg_out, s);
  }

  // -------- Phase 2b: path products, 8 leaves x 2 rows per thread --------
  {
    const int g8 = t & 31, rp = t >> 5;      // leaves g8*8..+8, rows 2rp,2rp+1
    const int Lb = g8 * 8;
#pragma unroll
    for (int rr = 0; rr < 2; ++rr) {
      const int row = rp * 2 + rr;
      const float* Lr = &L_s[row * LSTR];
      float pre = 1.f;
#pragma unroll
      for (int dd = 0; dd < 5; ++dd) {
        float p = Lr[(1 << dd) - 1 + (Lb >> (8 - dd))];
        float br = ((Lb >> (7 - dd)) & 1) ? (1.f - p) : p;
        pre *= fmaxf(br, 1e-5f);
      }
      float p5 = Lr[31 + g8];
      float s5a = fmaxf(p5, 1e-5f), s5b = fmaxf(1.f - p5, 1e-5f);
      float p6a = Lr[63 + 2 * g8], p6b = Lr[63 + 2 * g8 + 1];
      float p7v[4];
#pragma unroll
      for (int m = 0; m < 4; ++m) p7v[m] = Lr[127 + 4 * g8 + m];
      short8 ph;
#pragma unroll
      for (int j = 0; j < 8; ++j) {
        float s5 = (j & 4) ? s5b : s5a;
        float p6 = (j & 4) ? p6b : p6a;
        float s6 = fmaxf((j & 2) ? (1.f - p6) : p6, 1e-5f);
        float p7 = p7v[j >> 1];
        float s7 = fmaxf((j & 1) ? (1.f - p7) : p7, 1e-5f);
        ph[j] = f2bf(pre * s5 * s6 * s7);
      }
      *(short8*)&P_bf[row * PSTR + Lb] = ph;
    }
  }
  __syncthreads();

  // -------- Phase 2c: out[32][64] = P @ value via bf16 MFMA --------
  {
    const int tm = w & 1, tn = w >> 1;       // 2 x 4 tiles of 16x16
    floatx4 C = {0, 0, 0, 0};
    const short* vb = vt + (size_t)(tn * 16 + r16) * 256 + q * 8;
    const short* pa = &P_bf[(tm * 16 + r16) * PSTR + q * 8];
#pragma unroll
    for (int kc = 0; kc < 8; ++kc) {
      short8 A8 = *(const short8*)(pa + kc * 32);
      short8 B8 = *(const short8*)(vb + kc * 32);
      C = __builtin_amdgcn_mfma_f32_16x16x32_bf16(A8, B8, C, 0, 0, 0);
    }
    const int col = tn * 16 + r16;
#pragma unroll
    for (int r = 0; r < 4; ++r) {
      int row = tm * 16 + q * 4 + r;
      out[(size_t)(R0 + row) * O + col] = C[r];
    }
  }
}

extern "C" void kernel_launch(void* const* d_in, const int* in_sizes, int n_in,
                              void* d_out, int out_size, void* d_ws, size_t ws_size,
                              hipStream_t stream) {
  const float* x     = (const float*)d_in[0];
  const float* Ws    = (const float*)d_in[1];
  const float* bs    = (const float*)d_in[2];
  const float* value = (const float*)d_in[3];
  float* outp = (float*)d_out;
  float* reg_slot = outp + (size_t)8192 * O;          // index 524288
  short* wth = (short*)d_ws;                          // [256][512] bf16 hi
  short* wtl = wth + 256 * 512;                       // [256][512] bf16 lo
  short* vt  = wtl + 256 * 512;                       // [64][256]  value^T bf16

  sdt_pre<<<256, 512, 0, stream>>>(Ws, value, wth, wtl, vt, reg_slot);
  sdt_main<<<256, 512, 0, stream>>>(x, wth, wtl, vt, bs, outp, reg_slot);
}

// Round 5
// 97.152 us; speedup vs baseline: 1.1035x; 1.1035x over previous
//
#include <hip/hip_runtime.h>

// SDT forward. Phase 1: logits = x@W via bf16 split (xh@wh + xh@wl + xl@wh).
//   x tile converted ONCE into LDS (one barrier), then barrier-free K-loop:
//   A-frags via ds_read_b128, B-frags register-prefetched from L2-resident W^T.
// Phase 2: sigmoid+reg, grouped tree path-products, out = P@value via bf16 MFMA.
// MFMA 16x16x32_bf16 layouts (HW-verified, rounds 2-4 passed):
//   A/B^T: lane&15 -> row, (lane>>4)*8 -> k ;  C/D: col=lane&15, row=(lane>>4)*4+reg

typedef __attribute__((ext_vector_type(8))) short short8;
typedef __attribute__((ext_vector_type(4))) float floatx4;

constexpr int O = 64;
constexpr int XSTR = 520;   // x-tile LDS row stride (shorts): 1040 B, 16B-aligned, 2-way banks
constexpr int PSTR = 280;   // P_bf row stride (shorts)
constexpr int LSTR = 260;   // L_s row stride (floats)

__device__ __forceinline__ short f2bf(float f) {
  unsigned u = __builtin_bit_cast(unsigned, f);
  u += 0x7fffu + ((u >> 16) & 1u);          // RNE
  return (short)(u >> 16);
}
__device__ __forceinline__ float bf2f(short h) {
  unsigned u = ((unsigned)(unsigned short)h) << 16;
  return __builtin_bit_cast(float, u);
}
__device__ __forceinline__ int pk2(short a, short b) {
  return (int)((unsigned short)a | ((unsigned)(unsigned short)b << 16));
}

// ---- pre: W^T hi/lo bf16 via coalesced LDS transpose; value^T bf16; zero reg ----
__global__ __launch_bounds__(256) void sdt_pre(
    const float* __restrict__ Ws, const float* __restrict__ value,
    short* __restrict__ wth, short* __restrict__ wtl,
    short* __restrict__ vt, float* __restrict__ reg_slot)
{
  __shared__ short Th[32 * 72], Tl[32 * 72];
  const int bid = blockIdx.x, t = threadIdx.x;
  if (bid < 64) {                       // 8 k-tiles(64) x 8 n-tiles(32)
    const int k0 = (bid >> 3) * 64, n0 = (bid & 7) * 32;
    const int nn = t & 31, kk8 = t >> 5;
    const int ng = n0 + nn;
#pragma unroll
    for (int i = 0; i < 8; ++i) {
      const int kk = kk8 + i * 8;
      float f = (ng < 255) ? Ws[(size_t)(k0 + kk) * 255 + ng] : 0.f;
      short h = f2bf(f);
      Th[nn * 72 + kk] = h;
      Tl[nn * 72 + kk] = f2bf(f - bf2f(h));
    }
    __syncthreads();
    const int n2 = t >> 3, kg = (t & 7) * 8;
    short8 h8 = *(const short8*)&Th[n2 * 72 + kg];
    short8 l8 = *(const short8*)&Tl[n2 * 72 + kg];
    *(short8*)&wth[(size_t)(n0 + n2) * 512 + k0 + kg] = h8;
    *(short8*)&wtl[(size_t)(n0 + n2) * 512 + k0 + kg] = l8;
  } else {                              // value^T (tiny) + reg zero
    const int e0 = (bid - 64) * 4096 + t;
#pragma unroll
    for (int j = 0; j < 16; ++j) {
      const int e = e0 + j * 256;
      vt[e] = f2bf(value[(e & 255) * O + (e >> 8)]);
    }
    if (bid == 64 && t == 0) *reg_slot = 0.f;
  }
}

__global__ __launch_bounds__(512, 2) void sdt_main(
    const float* __restrict__ x, const short* __restrict__ wth,
    const short* __restrict__ wtl, const short* __restrict__ vt,
    const float* __restrict__ bs, float* __restrict__ out,
    float* __restrict__ reg_out)
{
  // Overlay: phase 1 uses xh|xl (66560 B); phase 2 reuses as L_s|P_bf (51232 B).
  __shared__ __align__(16) char smem[32 * XSTR * 2 * 2];
  short* xh_s = (short*)smem;                 // [32][520]
  short* xl_s = xh_s + 32 * XSTR;             // [32][520]
  float* L_s  = (float*)smem;                 // [32][260]
  short* P_bf = (short*)(smem + 32 * LSTR * 4);  // [32][280]
  __shared__ float red_s[8];

  const int t = threadIdx.x, lane = t & 63, w = t >> 6;   // 8 waves
  const int q = lane >> 4, r16 = lane & 15;
  const int R0 = blockIdx.x * 32;

  // -------- stage + convert x tile once (coalesced reads) --------
  {
    const int row = t >> 4, l4 = (t & 15) * 4;
    const float* xrow = x + (size_t)(R0 + row) * 512;
#pragma unroll
    for (int i = 0; i < 8; ++i) {
      const int k = l4 + i * 64;
      float4 v = *(const float4*)(xrow + k);
      short h0 = f2bf(v.x), h1 = f2bf(v.y), h2 = f2bf(v.z), h3 = f2bf(v.w);
      short g0 = f2bf(v.x - bf2f(h0)), g1 = f2bf(v.y - bf2f(h1));
      short g2 = f2bf(v.z - bf2f(h2)), g3 = f2bf(v.w - bf2f(h3));
      int2 hp; hp.x = pk2(h0, h1); hp.y = pk2(h2, h3);
      int2 lp; lp.x = pk2(g0, g1); lp.y = pk2(g2, g3);
      *(int2*)&xh_s[row * XSTR + k] = hp;
      *(int2*)&xl_s[row * XSTR + k] = lp;
    }
  }
  __syncthreads();

  // -------- barrier-free K-loop --------
  const short* pwh0 = wth + (size_t)(w * 32 + r16) * 512 + q * 8;
  const short* pwl0 = wtl + (size_t)(w * 32 + r16) * 512 + q * 8;
  const short* pwh1 = pwh0 + 16 * 512;
  const short* pwl1 = pwl0 + 16 * 512;
  const int aoff0 = r16 * XSTR + q * 8;
  const int aoff1 = (16 + r16) * XSTR + q * 8;

  floatx4 acc00 = {0,0,0,0}, acc01 = {0,0,0,0}, acc10 = {0,0,0,0}, acc11 = {0,0,0,0};

  short8 Bh0 = *(const short8*)(pwh0), Bl0 = *(const short8*)(pwl0);
  short8 Bh1 = *(const short8*)(pwh1), Bl1 = *(const short8*)(pwl1);

#pragma unroll
  for (int c = 0; c < 16; ++c) {
    short8 nh0, nl0, nh1, nl1;
    if (c < 15) {
      const int o = (c + 1) * 32;
      nh0 = *(const short8*)(pwh0 + o); nl0 = *(const short8*)(pwl0 + o);
      nh1 = *(const short8*)(pwh1 + o); nl1 = *(const short8*)(pwl1 + o);
    }
    short8 ah0 = *(const short8*)&xh_s[aoff0 + c * 32];
    short8 al0 = *(const short8*)&xl_s[aoff0 + c * 32];
    short8 ah1 = *(const short8*)&xh_s[aoff1 + c * 32];
    short8 al1 = *(const short8*)&xl_s[aoff1 + c * 32];

    acc00 = __builtin_amdgcn_mfma_f32_16x16x32_bf16(ah0, Bh0, acc00, 0, 0, 0);
    acc01 = __builtin_amdgcn_mfma_f32_16x16x32_bf16(ah0, Bh1, acc01, 0, 0, 0);
    acc10 = __builtin_amdgcn_mfma_f32_16x16x32_bf16(ah1, Bh0, acc10, 0, 0, 0);
    acc11 = __builtin_amdgcn_mfma_f32_16x16x32_bf16(ah1, Bh1, acc11, 0, 0, 0);
    acc00 = __builtin_amdgcn_mfma_f32_16x16x32_bf16(ah0, Bl0, acc00, 0, 0, 0);
    acc01 = __builtin_amdgcn_mfma_f32_16x16x32_bf16(ah0, Bl1, acc01, 0, 0, 0);
    acc10 = __builtin_amdgcn_mfma_f32_16x16x32_bf16(ah1, Bl0, acc10, 0, 0, 0);
    acc11 = __builtin_amdgcn_mfma_f32_16x16x32_bf16(ah1, Bl1, acc11, 0, 0, 0);
    acc00 = __builtin_amdgcn_mfma_f32_16x16x32_bf16(al0, Bh0, acc00, 0, 0, 0);
    acc01 = __builtin_amdgcn_mfma_f32_16x16x32_bf16(al0, Bh1, acc01, 0, 0, 0);
    acc10 = __builtin_amdgcn_mfma_f32_16x16x32_bf16(al1, Bh0, acc10, 0, 0, 0);
    acc11 = __builtin_amdgcn_mfma_f32_16x16x32_bf16(al1, Bh1, acc11, 0, 0, 0);

    if (c < 15) { Bh0 = nh0; Bl0 = nl0; Bh1 = nh1; Bl1 = nl1; }
  }
  __syncthreads();   // all waves done reading x tile before L_s overlays it

  // -------- epilogue: C frags -> L_s --------
  {
    const int c0 = w * 32 + r16, c1 = c0 + 16;
#pragma unroll
    for (int r = 0; r < 4; ++r) {
      int row0 = q * 4 + r, row1 = row0 + 16;
      L_s[row0 * LSTR + c0] = acc00[r];
      L_s[row0 * LSTR + c1] = acc01[r];
      L_s[row1 * LSTR + c0] = acc10[r];
      L_s[row1 * LSTR + c1] = acc11[r];
    }
  }
  __syncthreads();

  // -------- phase 2a: sigmoid (+bias), reg --------
  {
    const int col = t & 255, half = t >> 8;
    float rsum = 0.f;
    if (col < 255) {
      float b = bs[col];
      for (int r = half * 16; r < half * 16 + 16; ++r) {
        float z = L_s[r * LSTR + col] + b;
        float p = 1.f / (1.f + __expf(-z));
        L_s[r * LSTR + col] = p;                  // exclusive (col, half) owner
        rsum += __logf(fmaxf(p * (1.f - p), 1e-5f));
      }
      int dd = 31 - __clz(col + 1);
      rsum *= -0.5f / (8192.0f * (float)(1 << dd));
    }
#pragma unroll
    for (int off = 32; off; off >>= 1) rsum += __shfl_down(rsum, off, 64);
    if (lane == 0) red_s[w] = rsum;
  }
  __syncthreads();
  if (t == 0) {
    float s = 0.f;
#pragma unroll
    for (int i = 0; i < 8; ++i) s += red_s[i];
    atomicAdd(reg_out, s);
  }

  // -------- phase 2b: path products, 8 leaves x 2 rows per thread --------
  {
    const int g8 = t & 31, rp = t >> 5;
    const int Lb = g8 * 8;
#pragma unroll
    for (int rr = 0; rr < 2; ++rr) {
      const int row = rp * 2 + rr;
      const float* Lr = &L_s[row * LSTR];
      float pre = 1.f;
#pragma unroll
      for (int dd = 0; dd < 5; ++dd) {
        float p = Lr[(1 << dd) - 1 + (Lb >> (8 - dd))];
        float br = ((Lb >> (7 - dd)) & 1) ? (1.f - p) : p;
        pre *= fmaxf(br, 1e-5f);
      }
      float p5 = Lr[31 + g8];
      float s5a = fmaxf(p5, 1e-5f), s5b = fmaxf(1.f - p5, 1e-5f);
      float p6a = Lr[63 + 2 * g8], p6b = Lr[63 + 2 * g8 + 1];
      float p7v[4];
#pragma unroll
      for (int m = 0; m < 4; ++m) p7v[m] = Lr[127 + 4 * g8 + m];
      short8 ph;
#pragma unroll
      for (int j = 0; j < 8; ++j) {
        float s5 = (j & 4) ? s5b : s5a;
        float p6 = (j & 4) ? p6b : p6a;
        float s6 = fmaxf((j & 2) ? (1.f - p6) : p6, 1e-5f);
        float p7 = p7v[j >> 1];
        float s7 = fmaxf((j & 1) ? (1.f - p7) : p7, 1e-5f);
        ph[j] = f2bf(pre * s5 * s6 * s7);
      }
      *(short8*)&P_bf[row * PSTR + Lb] = ph;
    }
  }
  __syncthreads();

  // -------- phase 2c: out[32][64] = P @ value via bf16 MFMA --------
  {
    const int tm = w & 1, tn = w >> 1;
    floatx4 C = {0, 0, 0, 0};
    const short* vb = vt + (size_t)(tn * 16 + r16) * 256 + q * 8;
    const short* pa = &P_bf[(tm * 16 + r16) * PSTR + q * 8];
#pragma unroll
    for (int kc = 0; kc < 8; ++kc) {
      short8 A8 = *(const short8*)(pa + kc * 32);
      short8 B8 = *(const short8*)(vb + kc * 32);
      C = __builtin_amdgcn_mfma_f32_16x16x32_bf16(A8, B8, C, 0, 0, 0);
    }
    const int col = tn * 16 + r16;
#pragma unroll
    for (int r = 0; r < 4; ++r) {
      int row = tm * 16 + q * 4 + r;
      out[(size_t)(R0 + row) * O + col] = C[r];
    }
  }
}

extern "C" void kernel_launch(void* const* d_in, const int* in_sizes, int n_in,
                              void* d_out, int out_size, void* d_ws, size_t ws_size,
                              hipStream_t stream) {
  const float* x     = (const float*)d_in[0];
  const float* Ws    = (const float*)d_in[1];
  const float* bs    = (const float*)d_in[2];
  const float* value = (const float*)d_in[3];
  float* outp = (float*)d_out;
  float* reg_slot = outp + (size_t)8192 * O;          // index 524288
  short* wth = (short*)d_ws;                          // [256][512] bf16 hi
  short* wtl = wth + 256 * 512;                       // [256][512] bf16 lo
  short* vt  = wtl + 256 * 512;                       // [64][256]  value^T bf16

  sdt_pre<<<68, 256, 0, stream>>>(Ws, value, wth, wtl, vt, reg_slot);
  sdt_main<<<256, 512, 0, stream>>>(x, wth, wtl, vt, bs, outp, reg_slot);
}

// Round 6
// 84.355 us; speedup vs baseline: 1.2709x; 1.1517x over previous
//
#include <hip/hip_runtime.h>

// SDT forward, fp16 single-precision MFMA phase 1 (fp32 accumulate).
//   logits = x @ W (fp16 inputs; error ~2e-4, threshold ~0.13)
//   out[b,o] = sum_l P[b,l]*v[l,o], P = prod_d max(branch_p,1e-5)  (fp16 MFMA)
//   reg = sum_{b,node} (-0.5*2^-d/8192)*log(max(p(1-p),1e-5))      (fp32)
// W^T and value^T stored FRAGMENT-MAJOR: a wave's B-frag load is lane-linear
// (1 KB contiguous per instruction) instead of a 16-line gather.
// MFMA 16x16x32 layouts (HW-verified r2-r5): A/B^T lane&15->row, (lane>>4)*8->k;
// C/D: col=lane&15, row=(lane>>4)*4+reg.

typedef __attribute__((ext_vector_type(8))) _Float16 half8;
typedef __attribute__((ext_vector_type(4))) _Float16 half4;
typedef __attribute__((ext_vector_type(4))) float floatx4;

constexpr int O = 64;
constexpr int XSTR = 520;   // x-tile LDS row stride (halfs): 1040 B
constexpr int PSTR = 280;   // P_h row stride (halfs): 560 B (16B-aligned)
constexpr int LSTR = 260;   // L_s row stride (floats)

// ---- pre: W^T fp16 frag-major; value^T fp16 frag-major; zero reg ----
// wt layout: block (T*16+c) of 1024 B; lane=(q*16+r16); elem j:
//   wt[(T*16+c)*512 + lane*8 + j] = W[k= c*32+q*8+j][n= T*16+r16]
__global__ __launch_bounds__(256) void sdt_pre(
    const float* __restrict__ Ws, const float* __restrict__ value,
    _Float16* __restrict__ wt, _Float16* __restrict__ vt,
    float* __restrict__ reg_slot)
{
  const int bid = blockIdx.x, t = threadIdx.x;
  if (bid < 64) {                      // W: 8 k-rows per block, coalesced reads
    const int k0 = bid * 8;
    const int n = t;                   // 0..255
    const int T = n >> 4, r = n & 15;
    const int c = k0 >> 5, q = (k0 >> 3) & 3;
    _Float16 v8[8];
#pragma unroll
    for (int kk = 0; kk < 8; ++kk) {
      float f = (n < 255) ? Ws[(size_t)(k0 + kk) * 255 + n] : 0.f;
      v8[kk] = (_Float16)f;
    }
    *(half8*)&wt[(size_t)(T * 16 + c) * 512 + (q * 16 + r) * 8] = *(half8*)v8;
  } else {                             // value^T: 64 k-rows per block
    const int k0 = (bid - 64) * 64;
#pragma unroll
    for (int j = 0; j < 16; ++j) {
      int e = t + j * 256;             // 0..4095
      int k = k0 + (e >> 6), n = e & 63;
      float f = value[(size_t)k * O + n];
      int T = n >> 4, r = n & 15, kc = k >> 5, q = (k >> 3) & 3, jj = k & 7;
      vt[(size_t)(T * 8 + kc) * 512 + (q * 16 + r) * 8 + jj] = (_Float16)f;
    }
    if (bid == 64 && t == 0) *reg_slot = 0.f;
  }
}

__global__ __launch_bounds__(512, 2) void sdt_main(
    const float* __restrict__ x, const _Float16* __restrict__ wt,
    const _Float16* __restrict__ vt, const float* __restrict__ bs,
    float* __restrict__ out, float* __restrict__ reg_out)
{
  // Overlay: phase 1 x-tile fp16 (33280 B) / phase 2 L_s (33280 B) + P_h.
  __shared__ __align__(16) char smem[33280 + 17920];
  _Float16* xh_s = (_Float16*)smem;              // [32][520]
  float*    L_s  = (float*)smem;                 // [32][260]
  _Float16* P_h  = (_Float16*)(smem + 33280);    // [32][280]
  __shared__ float red_s[8];

  const int t = threadIdx.x, lane = t & 63, w = t >> 6;   // 8 waves
  const int q = lane >> 4, r16 = lane & 15;
  const int R0 = blockIdx.x * 32;

  // -------- stage + convert x tile once (coalesced) --------
  {
    const int row = t >> 4, l4 = (t & 15) * 4;
    const float* xrow = x + (size_t)(R0 + row) * 512;
#pragma unroll
    for (int i = 0; i < 8; ++i) {
      const int k = l4 + i * 64;
      float4 v = *(const float4*)(xrow + k);
      half4 h = {(_Float16)v.x, (_Float16)v.y, (_Float16)v.z, (_Float16)v.w};
      *(half4*)&xh_s[row * XSTR + k] = h;
    }
  }
  __syncthreads();

  // -------- barrier-free K-loop: 16 chunks of K=32, 4 MFMA each --------
  const _Float16* pb0 = wt + (size_t)(2 * w) * 16 * 512 + lane * 8;
  const _Float16* pb1 = wt + (size_t)(2 * w + 1) * 16 * 512 + lane * 8;
  const int a0off = r16 * XSTR, a1off = (16 + r16) * XSTR;

  floatx4 acc00 = {0,0,0,0}, acc01 = {0,0,0,0}, acc10 = {0,0,0,0}, acc11 = {0,0,0,0};
  half8 B0 = *(const half8*)pb0, B1 = *(const half8*)pb1;

#pragma unroll
  for (int c = 0; c < 16; ++c) {
    half8 n0, n1;
    if (c < 15) {
      n0 = *(const half8*)(pb0 + (c + 1) * 512);
      n1 = *(const half8*)(pb1 + (c + 1) * 512);
    }
    half8 a0 = *(const half8*)&xh_s[a0off + c * 32 + q * 8];
    half8 a1 = *(const half8*)&xh_s[a1off + c * 32 + q * 8];
    acc00 = __builtin_amdgcn_mfma_f32_16x16x32_f16(a0, B0, acc00, 0, 0, 0);
    acc01 = __builtin_amdgcn_mfma_f32_16x16x32_f16(a0, B1, acc01, 0, 0, 0);
    acc10 = __builtin_amdgcn_mfma_f32_16x16x32_f16(a1, B0, acc10, 0, 0, 0);
    acc11 = __builtin_amdgcn_mfma_f32_16x16x32_f16(a1, B1, acc11, 0, 0, 0);
    if (c < 15) { B0 = n0; B1 = n1; }
  }
  __syncthreads();   // all x-tile reads done before L_s overlays it

  // -------- epilogue: C frags -> L_s --------
  {
    const int c0 = w * 32 + r16, c1 = c0 + 16;
#pragma unroll
    for (int r = 0; r < 4; ++r) {
      int row0 = q * 4 + r, row1 = row0 + 16;
      L_s[row0 * LSTR + c0] = acc00[r];
      L_s[row0 * LSTR + c1] = acc01[r];
      L_s[row1 * LSTR + c0] = acc10[r];
      L_s[row1 * LSTR + c1] = acc11[r];
    }
  }
  __syncthreads();

  // -------- phase 2a: sigmoid (+bias), reg --------
  {
    const int col = t & 255, half = t >> 8;
    float rsum = 0.f;
    if (col < 255) {
      float b = bs[col];
      for (int r = half * 16; r < half * 16 + 16; ++r) {
        float z = L_s[r * LSTR + col] + b;
        float p = 1.f / (1.f + __expf(-z));
        L_s[r * LSTR + col] = p;                  // exclusive (col, half) owner
        rsum += __logf(fmaxf(p * (1.f - p), 1e-5f));
      }
      int dd = 31 - __clz(col + 1);
      rsum *= -0.5f / (8192.0f * (float)(1 << dd));
    }
#pragma unroll
    for (int off = 32; off; off >>= 1) rsum += __shfl_down(rsum, off, 64);
    if (lane == 0) red_s[w] = rsum;
  }
  __syncthreads();
  if (t == 0) {
    float s = 0.f;
#pragma unroll
    for (int i = 0; i < 8; ++i) s += red_s[i];
    atomicAdd(reg_out, s);
  }

  // -------- phase 2b: path products, 8 leaves x 2 rows per thread --------
  {
    const int g8 = t & 31, rp = t >> 5;
    const int Lb = g8 * 8;
#pragma unroll
    for (int rr = 0; rr < 2; ++rr) {
      const int row = rp * 2 + rr;
      const float* Lr = &L_s[row * LSTR];
      float pre = 1.f;
#pragma unroll
      for (int dd = 0; dd < 5; ++dd) {
        float p = Lr[(1 << dd) - 1 + (Lb >> (8 - dd))];
        float br = ((Lb >> (7 - dd)) & 1) ? (1.f - p) : p;
        pre *= fmaxf(br, 1e-5f);
      }
      float p5 = Lr[31 + g8];
      float s5a = fmaxf(p5, 1e-5f), s5b = fmaxf(1.f - p5, 1e-5f);
      float p6a = Lr[63 + 2 * g8], p6b = Lr[63 + 2 * g8 + 1];
      float p7v[4];
#pragma unroll
      for (int m = 0; m < 4; ++m) p7v[m] = Lr[127 + 4 * g8 + m];
      _Float16 ph[8];
#pragma unroll
      for (int j = 0; j < 8; ++j) {
        float s5 = (j & 4) ? s5b : s5a;
        float p6 = (j & 4) ? p6b : p6a;
        float s6 = fmaxf((j & 2) ? (1.f - p6) : p6, 1e-5f);
        float p7 = p7v[j >> 1];
        float s7 = fmaxf((j & 1) ? (1.f - p7) : p7, 1e-5f);
        ph[j] = (_Float16)(pre * s5 * s6 * s7);
      }
      *(half8*)&P_h[row * PSTR + Lb] = *(half8*)ph;
    }
  }
  __syncthreads();

  // -------- phase 2c: out[32][64] = P @ value via fp16 MFMA --------
  {
    const int tm = w & 1, tn = w >> 1;       // 2 m-tiles x 4 n-tiles of 16
    floatx4 C = {0, 0, 0, 0};
    const _Float16* vb = vt + (size_t)(tn * 8) * 512 + lane * 8;
    const _Float16* pa = &P_h[(tm * 16 + r16) * PSTR + q * 8];
#pragma unroll
    for (int kc = 0; kc < 8; ++kc) {
      half8 A8 = *(const half8*)(pa + kc * 32);
      half8 B8 = *(const half8*)(vb + kc * 512);
      C = __builtin_amdgcn_mfma_f32_16x16x32_f16(A8, B8, C, 0, 0, 0);
    }
    const int col = tn * 16 + r16;
#pragma unroll
    for (int r = 0; r < 4; ++r) {
      int row = tm * 16 + q * 4 + r;
      out[(size_t)(R0 + row) * O + col] = C[r];
    }
  }
}

extern "C" void kernel_launch(void* const* d_in, const int* in_sizes, int n_in,
                              void* d_out, int out_size, void* d_ws, size_t ws_size,
                              hipStream_t stream) {
  const float* x     = (const float*)d_in[0];
  const float* Ws    = (const float*)d_in[1];
  const float* bs    = (const float*)d_in[2];
  const float* value = (const float*)d_in[3];
  float* outp = (float*)d_out;
  float* reg_slot = outp + (size_t)8192 * O;          // index 524288
  _Float16* wt = (_Float16*)d_ws;                     // frag-major W^T fp16, 256 KB
  _Float16* vt = wt + 256 * 512;                      // frag-major value^T fp16, 32 KB

  sdt_pre<<<68, 256, 0, stream>>>(Ws, value, wt, vt, reg_slot);
  sdt_main<<<256, 512, 0, stream>>>(x, wt, vt, bs, outp, reg_slot);
}